// Round 4
// baseline (177.138 us; speedup 1.0000x reference)
//
#include <hip/hip_runtime.h>
#include <hip/hip_bf16.h>

#define F 1024
#define B_ROWS 16384
#define KSEG 512
#define NITER (KSEG / 32)  // 16

typedef short v8s __attribute__((ext_vector_type(8)));
typedef float v4f __attribute__((ext_vector_type(4)));
typedef unsigned short v8u __attribute__((ext_vector_type(8)));
typedef unsigned short ushort_t;

__device__ __forceinline__ unsigned short f2bf(float f) {
    unsigned int u = __builtin_bit_cast(unsigned int, f);
    u = (u + 0x7FFFu + ((u >> 16) & 1u)) >> 16;  // RNE
    return (unsigned short)u;
}
__device__ __forceinline__ float bf2f(unsigned short h) {
    return __builtin_bit_cast(float, (unsigned int)h << 16);
}

// async global->LDS, 16B per lane. LDS dest = wave-uniform base + lane*16.
__device__ __forceinline__ void gload_lds16(const ushort_t* g, ushort_t* l) {
    __builtin_amdgcn_global_load_lds(
        (const __attribute__((address_space(1))) unsigned int*)g,
        (__attribute__((address_space(3))) unsigned int*)l,
        16, 0, 0);
}

// Fused prep: [0,64) zero rowacc; [64,4160) build A = 0.5*(W+W^T) bf16;
// [4160,12352) convert X fp32->bf16, 8 elements/thread.
__global__ __launch_bounds__(256) void prep_kernel(
        const float* __restrict__ w, const float* __restrict__ x,
        ushort_t* __restrict__ A, ushort_t* __restrict__ Xb,
        float* __restrict__ acc) {
    const int bid = blockIdx.x;
    if (bid < 64) {
        acc[bid * 256 + threadIdx.x] = 0.0f;
    } else if (bid < 64 + 4096) {
        int tid = (bid - 64) * 256 + threadIdx.x;  // 0 .. F*F-1
        int i = tid >> 10, j = tid & (F - 1);
        float v = 0.0f;
        if (i != j) {
            int a = min(i, j), b = max(i, j);
            int k = a * (F - 1) - (a * (a - 1)) / 2 + (b - a - 1);
            v = 0.5f * w[k];  // uncoalesced half is L2-resident (w = 2MB)
        }
        A[tid] = f2bf(v);
    } else {
        int tid = (bid - 4160) * 256 + threadIdx.x;
        size_t idx = (size_t)tid * 8;
        float4 v0 = *(const float4*)(x + idx);
        float4 v1 = *(const float4*)(x + idx + 4);
        v8u o;
        o[0] = f2bf(v0.x); o[1] = f2bf(v0.y); o[2] = f2bf(v0.z); o[3] = f2bf(v0.w);
        o[4] = f2bf(v1.x); o[5] = f2bf(v1.y); o[6] = f2bf(v1.z); o[7] = f2bf(v1.w);
        *(v8u*)(Xb + idx) = o;
    }
}

// Split-K GEMM with rotated K-segments + fused row-dot epilogue.
// Block (n,z,y): M-rows [y*128,+128), N-cols [n*128,+128),
// K-segment [(n*128 + z*512) mod 1024, +512)  (the two z's partition K).
// z=0's first 4 iterations stage exactly the N-tile columns of X ->
// captured from LDS into registers for the epilogue (no global reads).
// z=1 reads bf16 Xb from global in the epilogue.
// XCD swizzle: blocks sharing an M-row-tile run consecutively on one XCD.
__global__ __launch_bounds__(256) void gemm_kernel(
        const ushort_t* __restrict__ Xb,   // [B_ROWS][F] bf16
        const ushort_t* __restrict__ A,    // [F][F] bf16 symmetric
        float*         __restrict__ rowacc) {
    __shared__ ushort_t As[128 * 32];  // 8 KB
    __shared__ ushort_t Bs[128 * 32];  // 8 KB

    // ---- swizzled block decode: xcd = f&7 (HW round-robin heuristic) ----
    const int f   = blockIdx.x;          // 0..2047
    const int xcd = f & 7;
    const int s   = f >> 3;              // 0..255 (per-XCD sequence)
    const int wz  = s & 15;              // 16 (n,z) combos share one y
    const int n   = wz & 7;
    const int z   = wz >> 3;
    const int blockM = (xcd * 16 + (s >> 4)) * 128;
    const int blockN = n * 128;
    const int kStart = blockN + z * KSEG;  // wrapped per-iteration

    const int tid   = threadIdx.x;
    const int lane  = tid & 63;
    const int wave  = tid >> 6;
    const int waveM = wave >> 1;     // 0..1
    const int waveN = wave & 1;      // 0..1
    const int quad  = lane >> 4;     // 0..3
    const int l16   = lane & 15;

    // ---- staging addresses (XOR source-swizzle, verified 0 conflicts) ----
    const int lrow = lane >> 2;                       // 0..15
    const int csrc = (lane & 3) ^ ((lane >> 3) & 3);  // swizzled source chunk
    const int rowA0 = wave * 32 + lrow;
    const int rowA1 = wave * 32 + 16 + lrow;

    const ushort_t* pA0 = Xb + (size_t)(blockM + rowA0) * F + csrc * 8;
    const ushort_t* pA1 = Xb + (size_t)(blockM + rowA1) * F + csrc * 8;
    const ushort_t* pB0 = A + (size_t)(blockN + rowA0) * F + csrc * 8;
    const ushort_t* pB1 = A + (size_t)(blockN + rowA1) * F + csrc * 8;
    ushort_t* lA0 = As + (wave * 32) * 32;       // +lane*16B implicit
    ushort_t* lA1 = As + (wave * 32 + 16) * 32;
    ushort_t* lB0 = Bs + (wave * 32) * 32;
    ushort_t* lB1 = Bs + (wave * 32 + 16) * 32;

    // fragment-read swizzle: row R = base16 + l16, (R>>1)&3 == (l16>>1)&3
    const int swz = quad ^ ((l16 >> 1) & 3);

    v4f acc[4][4];
#pragma unroll
    for (int i = 0; i < 4; i++)
#pragma unroll
        for (int j = 0; j < 4; j++) acc[i][j] = (v4f)(0.0f);

    // epilogue X capture (z==0 blocks): packed bf16 pairs, ni={0,1} / {2,3}
    unsigned cap01[16], cap23[16];

    for (int it = 0; it < NITER; ++it) {
        const int kk = (kStart + it * 32) & (F - 1);
        __syncthreads();  // previous tile's reads complete before overwrite
        gload_lds16(pA0 + kk, lA0);
        gload_lds16(pA1 + kk, lA1);
        gload_lds16(pB0 + kk, lB0);
        gload_lds16(pB1 + kk, lB1);
        __syncthreads();  // drains vmcnt(0): staged data visible

        if (z == 0 && (it >> 1) == waveN) {
            // As holds X[blockM..+128][blockN + it*32 .. +32]; grab the two
            // 16-apart elements (e=l16, e=16+l16) for each of this lane's
            // 16 output rows. Source chunk c at LDS position c ^ ((row>>1)&3).
            const int itr = it & 1;  // 0 -> ni 0,1 ; 1 -> ni 2,3
#pragma unroll
            for (int bi = 0; bi < 16; ++bi) {
                const int lb = waveM * 64 + (bi >> 2) * 16 + quad * 4 + (bi & 3);
                const int sw = (lb >> 1) & 3;
                const int c0 = (l16 >> 3);
                const int c1 = 2 + (l16 >> 3);
                unsigned short u0 = As[lb * 32 + ((c0 ^ sw) * 8) + (l16 & 7)];
                unsigned short u1 = As[lb * 32 + ((c1 ^ sw) * 8) + (l16 & 7)];
                unsigned v = (unsigned)u0 | ((unsigned)u1 << 16);
                if (itr == 0) cap01[bi] = v; else cap23[bi] = v;
            }
        }

        v8s af[4], bfr[4];
#pragma unroll
        for (int mi = 0; mi < 4; mi++)
            af[mi] = *(const v8s*)(As + (waveM * 64 + mi * 16 + l16) * 32 + swz * 8);
#pragma unroll
        for (int ni = 0; ni < 4; ni++)
            bfr[ni] = *(const v8s*)(Bs + (waveN * 64 + ni * 16 + l16) * 32 + swz * 8);
#pragma unroll
        for (int mi = 0; mi < 4; mi++)
#pragma unroll
            for (int ni = 0; ni < 4; ni++)
                acc[mi][ni] = __builtin_amdgcn_mfma_f32_16x16x32_bf16(
                    af[mi], bfr[ni], acc[mi][ni], 0, 0, 0);
    }

    // Epilogue: C/D mapping (verified): col = lane&15, row = quad*4 + reg.
    // out_b partial = sum_ni acc[mi][ni][r] * x[b][blockN + waveN*64 + ni*16 + l16]
#pragma unroll
    for (int mi = 0; mi < 4; mi++) {
#pragma unroll
        for (int r = 0; r < 4; r++) {
            const int b = blockM + waveM * 64 + mi * 16 + quad * 4 + r;
            float p;
            if (z == 0) {
                const int bi = mi * 4 + r;
                p = acc[mi][0][r] * bf2f((unsigned short)(cap01[bi] & 0xffffu))
                  + acc[mi][1][r] * bf2f((unsigned short)(cap01[bi] >> 16))
                  + acc[mi][2][r] * bf2f((unsigned short)(cap23[bi] & 0xffffu))
                  + acc[mi][3][r] * bf2f((unsigned short)(cap23[bi] >> 16));
            } else {
                const ushort_t* xr = Xb + (size_t)b * F + blockN + waveN * 64 + l16;
                p = acc[mi][0][r] * bf2f(xr[0])
                  + acc[mi][1][r] * bf2f(xr[16])
                  + acc[mi][2][r] * bf2f(xr[32])
                  + acc[mi][3][r] * bf2f(xr[48]);
            }
            p += __shfl_xor(p, 1);
            p += __shfl_xor(p, 2);
            p += __shfl_xor(p, 4);
            p += __shfl_xor(p, 8);
            if (l16 == 0) atomicAdd(&rowacc[b], p);
        }
    }
}

__global__ void sigmoid_kernel(const float* __restrict__ acc, float* __restrict__ out) {
    int b = blockIdx.x * blockDim.x + threadIdx.x;
    out[b] = 1.0f / (1.0f + __expf(-acc[b]));
}

// Correctness fallback if workspace is too small: direct per-row computation.
__global__ void fallback_kernel(const float* __restrict__ x, const float* __restrict__ w,
                                float* __restrict__ out) {
    __shared__ float xs[F];
    __shared__ float partial[4];
    const int b = blockIdx.x;
    for (int i = threadIdx.x; i < F; i += 256) xs[i] = x[(size_t)b * F + i];
    __syncthreads();
    float s = 0.0f;
    for (int i = threadIdx.x; i < F - 1; i += 256) {
        const float xi = xs[i];
        const int kbase = i * (F - 1) - (i * (i - 1)) / 2 - i - 1;
        for (int j = i + 1; j < F; j++) s += w[kbase + j] * xi * xs[j];
    }
    for (int off = 32; off; off >>= 1) s += __shfl_down(s, off);
    if ((threadIdx.x & 63) == 0) partial[threadIdx.x >> 6] = s;
    __syncthreads();
    if (threadIdx.x == 0) {
        float t = partial[0] + partial[1] + partial[2] + partial[3];
        out[b] = 1.0f / (1.0f + __expf(-t));
    }
}

extern "C" void kernel_launch(void* const* d_in, const int* in_sizes, int n_in,
                              void* d_out, int out_size, void* d_ws, size_t ws_size,
                              hipStream_t stream) {
    const float* x = (const float*)d_in[0];
    const float* w = (const float*)d_in[1];
    float* out = (float*)d_out;

    const size_t acc_bytes = 65536;                       // 16384 fp32 (rounded)
    const size_t A_bytes   = (size_t)F * F * 2;           // 2 MiB bf16
    const size_t Xb_bytes  = (size_t)B_ROWS * F * 2;      // 32 MiB bf16
    const size_t needed = acc_bytes + A_bytes + Xb_bytes;

    if (ws_size < needed) {
        fallback_kernel<<<B_ROWS, 256, 0, stream>>>(x, w, out);
        return;
    }

    float*    acc = (float*)d_ws;
    ushort_t* A   = (ushort_t*)((char*)d_ws + acc_bytes);
    ushort_t* Xb  = (ushort_t*)((char*)d_ws + acc_bytes + A_bytes);

    prep_kernel<<<64 + 4096 + 8192, 256, 0, stream>>>(w, x, A, Xb, acc);
    gemm_kernel<<<2048, 256, 0, stream>>>(Xb, A, acc);
    sigmoid_kernel<<<B_ROWS / 256, 256, 0, stream>>>(acc, out);
}

// Round 5
// 167.924 us; speedup vs baseline: 1.0549x; 1.0549x over previous
//
#include <hip/hip_runtime.h>
#include <hip/hip_bf16.h>

#define F 1024
#define B_ROWS 16384
#define KSEG 512
#define BK 64
#define NITER (KSEG / BK)  // 8

typedef short v8s __attribute__((ext_vector_type(8)));
typedef float v4f __attribute__((ext_vector_type(4)));
typedef unsigned short v8u __attribute__((ext_vector_type(8)));
typedef unsigned short ushort_t;

__device__ __forceinline__ unsigned short f2bf(float f) {
    unsigned int u = __builtin_bit_cast(unsigned int, f);
    u = (u + 0x7FFFu + ((u >> 16) & 1u)) >> 16;  // RNE
    return (unsigned short)u;
}
__device__ __forceinline__ float bf2f(unsigned short h) {
    return __builtin_bit_cast(float, (unsigned int)h << 16);
}

// async global->LDS, 16B per lane. LDS dest = wave-uniform base + lane*16.
__device__ __forceinline__ void gload_lds16(const ushort_t* g, ushort_t* l) {
    __builtin_amdgcn_global_load_lds(
        (const __attribute__((address_space(1))) unsigned int*)g,
        (__attribute__((address_space(3))) unsigned int*)l,
        16, 0, 0);
}

// Fused prep: [0,64) zero rowacc; [64,4160) build A = 0.5*(W+W^T) bf16;
// [4160,12352) convert X fp32->bf16, 8 elements/thread.
__global__ __launch_bounds__(256) void prep_kernel(
        const float* __restrict__ w, const float* __restrict__ x,
        ushort_t* __restrict__ A, ushort_t* __restrict__ Xb,
        float* __restrict__ acc) {
    const int bid = blockIdx.x;
    if (bid < 64) {
        acc[bid * 256 + threadIdx.x] = 0.0f;
    } else if (bid < 64 + 4096) {
        int tid = (bid - 64) * 256 + threadIdx.x;  // 0 .. F*F-1
        int i = tid >> 10, j = tid & (F - 1);
        float v = 0.0f;
        if (i != j) {
            int a = min(i, j), b = max(i, j);
            int k = a * (F - 1) - (a * (a - 1)) / 2 + (b - a - 1);
            v = 0.5f * w[k];  // uncoalesced half is L2-resident (w = 2MB)
        }
        A[tid] = f2bf(v);
    } else {
        int tid = (bid - 4160) * 256 + threadIdx.x;
        size_t idx = (size_t)tid * 8;
        float4 v0 = *(const float4*)(x + idx);
        float4 v1 = *(const float4*)(x + idx + 4);
        v8u o;
        o[0] = f2bf(v0.x); o[1] = f2bf(v0.y); o[2] = f2bf(v0.z); o[3] = f2bf(v0.w);
        o[4] = f2bf(v1.x); o[5] = f2bf(v1.y); o[6] = f2bf(v1.z); o[7] = f2bf(v1.w);
        *(v8u*)(Xb + idx) = o;
    }
}

// Split-K GEMM, BK=64 per barrier pair (two proven 128x32 sub-tiles per
// stage -> 8 barrier-drains instead of 16), fused bf16 row-dot epilogue.
// Block (xcd-swizzled): M-rows [blockM,+128), N-cols [blockN,+128),
// K in [z*512, +512). LDS layout per sub-tile: 64B rows, XOR source-swizzle
// (pos c of row r holds global chunk c ^ ((r>>1)&3)) -> 0 bank conflicts
// (verified rounds 2-4).
__global__ __launch_bounds__(256) void gemm_kernel(
        const ushort_t* __restrict__ Xb,   // [B_ROWS][F] bf16
        const ushort_t* __restrict__ A,    // [F][F] bf16 symmetric
        float*         __restrict__ rowacc) {
    __shared__ ushort_t As[2 * 128 * 32];  // 16 KB (two 128x32 sub-tiles)
    __shared__ ushort_t Bs[2 * 128 * 32];  // 16 KB

    // ---- XCD swizzle: 16 (n,z) blocks of one M-tile run on one XCD ----
    const int f   = blockIdx.x;          // 0..2047
    const int xcd = f & 7;
    const int s   = f >> 3;              // 0..255
    const int n   = s & 7;
    const int z   = (s >> 3) & 1;
    const int y   = s >> 4;              // 0..15
    const int blockM = (xcd * 16 + y) * 128;
    const int blockN = n * 128;
    const int kBase  = z * KSEG;

    const int tid   = threadIdx.x;
    const int lane  = tid & 63;
    const int wave  = tid >> 6;
    const int waveM = wave >> 1;     // 0..1
    const int waveN = wave & 1;      // 0..1
    const int quad  = lane >> 4;     // 0..3
    const int l16   = lane & 15;

    // ---- staging addresses (per sub-tile = round-2 pattern) ----
    const int lrow = lane >> 2;                       // 0..15
    const int csrc = (lane & 3) ^ ((lane >> 3) & 3);  // swizzled source chunk
    const int rowA0 = wave * 32 + lrow;
    const int rowA1 = wave * 32 + 16 + lrow;

    const ushort_t* pA0 = Xb + (size_t)(blockM + rowA0) * F + kBase + csrc * 8;
    const ushort_t* pA1 = Xb + (size_t)(blockM + rowA1) * F + kBase + csrc * 8;
    const ushort_t* pB0 = A + (size_t)(blockN + rowA0) * F + kBase + csrc * 8;
    const ushort_t* pB1 = A + (size_t)(blockN + rowA1) * F + kBase + csrc * 8;
    ushort_t* lA0 = As + (wave * 32) * 32;       // +lane*16B implicit
    ushort_t* lA1 = As + (wave * 32 + 16) * 32;
    ushort_t* lB0 = Bs + (wave * 32) * 32;
    ushort_t* lB1 = Bs + (wave * 32 + 16) * 32;

    // fragment-read swizzle: row R = base16 + l16, (R>>1)&3 == (l16>>1)&3
    const int swz = quad ^ ((l16 >> 1) & 3);

    v4f acc[4][4];
#pragma unroll
    for (int i = 0; i < 4; i++)
#pragma unroll
        for (int j = 0; j < 4; j++) acc[i][j] = (v4f)(0.0f);

    for (int it = 0; it < NITER; ++it) {
        __syncthreads();  // previous tile's reads complete before overwrite
#pragma unroll
        for (int st = 0; st < 2; ++st) {
            const int ko = st * 32;          // sub-tile k-offset (elements)
            const int lo = st * 4096;        // sub-tile LDS offset (elements)
            gload_lds16(pA0 + ko, lA0 + lo);
            gload_lds16(pA1 + ko, lA1 + lo);
            gload_lds16(pB0 + ko, lB0 + lo);
            gload_lds16(pB1 + ko, lB1 + lo);
        }
        pA0 += BK; pA1 += BK; pB0 += BK; pB1 += BK;
        __syncthreads();  // drains vmcnt(0): staged data visible

#pragma unroll
        for (int st = 0; st < 2; ++st) {
            const int lo = st * 4096;
            v8s af[4], bfr[4];
#pragma unroll
            for (int mi = 0; mi < 4; mi++)
                af[mi] = *(const v8s*)(As + lo + (waveM * 64 + mi * 16 + l16) * 32 + swz * 8);
#pragma unroll
            for (int ni = 0; ni < 4; ni++)
                bfr[ni] = *(const v8s*)(Bs + lo + (waveN * 64 + ni * 16 + l16) * 32 + swz * 8);
#pragma unroll
            for (int mi = 0; mi < 4; mi++)
#pragma unroll
                for (int ni = 0; ni < 4; ni++)
                    acc[mi][ni] = __builtin_amdgcn_mfma_f32_16x16x32_bf16(
                        af[mi], bfr[ni], acc[mi][ni], 0, 0, 0);
        }
    }

    // Epilogue: C/D mapping (verified): col = lane&15, row = quad*4 + reg.
    // partial_b = sum_ni acc[mi][ni][r] * x_bf16[b][blockN + waveN*64 + ni*16 + l16]
#pragma unroll
    for (int mi = 0; mi < 4; mi++) {
#pragma unroll
        for (int r = 0; r < 4; r++) {
            const int b = blockM + waveM * 64 + mi * 16 + quad * 4 + r;
            const ushort_t* xr = Xb + (size_t)b * F + blockN + waveN * 64 + l16;
            float p = acc[mi][0][r] * bf2f(xr[0])
                    + acc[mi][1][r] * bf2f(xr[16])
                    + acc[mi][2][r] * bf2f(xr[32])
                    + acc[mi][3][r] * bf2f(xr[48]);
            p += __shfl_xor(p, 1);
            p += __shfl_xor(p, 2);
            p += __shfl_xor(p, 4);
            p += __shfl_xor(p, 8);
            if (l16 == 0) atomicAdd(&rowacc[b], p);
        }
    }
}

__global__ void sigmoid_kernel(const float* __restrict__ acc, float* __restrict__ out) {
    int b = blockIdx.x * blockDim.x + threadIdx.x;
    out[b] = 1.0f / (1.0f + __expf(-acc[b]));
}

// Correctness fallback if workspace is too small: direct per-row computation.
__global__ void fallback_kernel(const float* __restrict__ x, const float* __restrict__ w,
                                float* __restrict__ out) {
    __shared__ float xs[F];
    __shared__ float partial[4];
    const int b = blockIdx.x;
    for (int i = threadIdx.x; i < F; i += 256) xs[i] = x[(size_t)b * F + i];
    __syncthreads();
    float s = 0.0f;
    for (int i = threadIdx.x; i < F - 1; i += 256) {
        const float xi = xs[i];
        const int kbase = i * (F - 1) - (i * (i - 1)) / 2 - i - 1;
        for (int j = i + 1; j < F; j++) s += w[kbase + j] * xi * xs[j];
    }
    for (int off = 32; off; off >>= 1) s += __shfl_down(s, off);
    if ((threadIdx.x & 63) == 0) partial[threadIdx.x >> 6] = s;
    __syncthreads();
    if (threadIdx.x == 0) {
        float t = partial[0] + partial[1] + partial[2] + partial[3];
        out[b] = 1.0f / (1.0f + __expf(-t));
    }
}

extern "C" void kernel_launch(void* const* d_in, const int* in_sizes, int n_in,
                              void* d_out, int out_size, void* d_ws, size_t ws_size,
                              hipStream_t stream) {
    const float* x = (const float*)d_in[0];
    const float* w = (const float*)d_in[1];
    float* out = (float*)d_out;

    const size_t acc_bytes = 65536;                       // 16384 fp32 (rounded)
    const size_t A_bytes   = (size_t)F * F * 2;           // 2 MiB bf16
    const size_t Xb_bytes  = (size_t)B_ROWS * F * 2;      // 32 MiB bf16
    const size_t needed = acc_bytes + A_bytes + Xb_bytes;

    if (ws_size < needed) {
        fallback_kernel<<<B_ROWS, 256, 0, stream>>>(x, w, out);
        return;
    }

    float*    acc = (float*)d_ws;
    ushort_t* A   = (ushort_t*)((char*)d_ws + acc_bytes);
    ushort_t* Xb  = (ushort_t*)((char*)d_ws + acc_bytes + A_bytes);

    prep_kernel<<<64 + 4096 + 8192, 256, 0, stream>>>(w, x, A, Xb, acc);
    gemm_kernel<<<2048, 256, 0, stream>>>(Xb, A, acc);
    sigmoid_kernel<<<B_ROWS / 256, 256, 0, stream>>>(acc, out);
}